// Round 13
// baseline (328.377 us; speedup 1.0000x reference)
//
#include <hip/hip_runtime.h>

#define NENT    100000
#define NENTPAD 100096      // 782*128, padded for combine staging
#define NREL    100
#define DIM     128
#define NBASES  10
#define NEDGES  600000
#define CH      64          // edges per chunk (4-wave blocks, 3 blocks/CU)
#define TMAX    9600        // >= ceil(NEDGES/CH) + NREL
#define PADE    606336      // >= NEDGES + NREL*(CH-1)
#define NB_ESCAN 98
#define EPB     4096        // edges per sort block
#define NBH     147         // ceil(NEDGES/EPB)
#define NPERS   768         // persistent edge-kernel grid (3 blocks/CU)

typedef unsigned short u16;
typedef unsigned int   u32;
typedef __bf16  bf16x8 __attribute__((ext_vector_type(8)));
typedef float   f32x16 __attribute__((ext_vector_type(16)));

static __device__ __forceinline__ u16 f2bf(float f) {
  u32 u = __float_as_uint(f);
  u = (u + 0x7fffu + ((u >> 16) & 1u)) >> 16;
  return (u16)u;
}
static __device__ __forceinline__ float bf2f(u32 h) {
  return __uint_as_float(h << 16);
}
static __device__ __forceinline__ u32 pk2(float a, float b) {
  return (u32)f2bf(a) | ((u32)f2bf(b) << 16);
}
#define GLD16(g, l) __builtin_amdgcn_global_load_lds( \
    (__attribute__((address_space(1))) u32*)(g), \
    (__attribute__((address_space(3))) u32*)(l), 16, 0, 0)

// ---------- phase 1: per-block relation histogram + indegree ----------
__global__ __launch_bounds__(1024) void k_hist2(const int* __restrict__ tgt,
                                                const int* __restrict__ rel,
                                                int* __restrict__ indeg,
                                                int* __restrict__ hist) {
  __shared__ int h[NREL];
  int tid = threadIdx.x, blk = blockIdx.x;
  if (tid < NREL) h[tid] = 0;
  __syncthreads();
  int base = blk * EPB;
  int nv = NEDGES - base; if (nv > EPB) nv = EPB;
#pragma unroll
  for (int k = 0; k < 4; ++k) {
    int j = tid + k * 1024;
    if (j < nv) {
      int i = base + j;
      atomicAdd(&indeg[tgt[i]], 1);
      atomicAdd(&h[rel[i]], 1);
    }
  }
  __syncthreads();
  if (tid < NREL) hist[tid * NBH + blk] = h[tid];
}

// ---------- phase 2: chunk table + absolute per-(rel,block) offsets ----------
__global__ __launch_bounds__(1024) void k_scan2(int* __restrict__ hist,
                                                int* __restrict__ chunk_rel,
                                                int* __restrict__ chunk_start,
                                                int* __restrict__ chunk_valid,
                                                int* __restrict__ chunkT) {
  __shared__ int sh[NREL * NBH];   // 57.4 KB
  __shared__ int cnt[NREL];
  __shared__ int cb[128];
  int tid = threadIdx.x;
  for (int i = tid; i < NREL * NBH; i += 1024) sh[i] = hist[i];
  __syncthreads();
  if (tid < NREL) {
    int s = 0;
    for (int b = 0; b < NBH; ++b) s += sh[tid * NBH + b];
    cnt[tid] = s;
  }
  __syncthreads();
  if (tid < 128) cb[tid] = (tid < NREL) ? (cnt[tid] + CH - 1) / CH : 0;
  __syncthreads();
  for (int d = 1; d < 128; d <<= 1) {
    int t = 0;
    if (tid < 128 && tid >= d) t = cb[tid - d];
    __syncthreads();
    if (tid < 128) cb[tid] += t;
    __syncthreads();
  }
  if (tid < NREL) {
    int c = cnt[tid];
    int nch = (c + CH - 1) / CH;
    int cb0 = cb[tid] - nch;
    int poff = cb0 * CH;
    for (int i = 0; i < nch; ++i) {
      chunk_rel[cb0 + i] = tid;
      chunk_start[cb0 + i] = (cb0 + i) * CH;
      int v = c - i * CH;
      if (v > CH) v = CH;
      chunk_valid[cb0 + i] = v;
    }
    int run = poff;
    for (int b = 0; b < NBH; ++b) {
      int t = sh[tid * NBH + b];
      sh[tid * NBH + b] = run;
      run += t;
    }
  }
  if (tid == 127) *chunkT = cb[127];
  __syncthreads();
  for (int i = tid; i < NREL * NBH; i += 1024) hist[i] = sh[i];
}

// ---------- phase 3: staged, relation-grouped scatter (coalesced writes) ----------
__global__ __launch_bounds__(1024) void k_scatter2(const int* __restrict__ src,
                                                   const int* __restrict__ tgt,
                                                   const int* __restrict__ rel,
                                                   const int* __restrict__ hist,
                                                   const int* __restrict__ row_ptr,
                                                   int* __restrict__ fill_t,
                                                   int* __restrict__ es,
                                                   int* __restrict__ tp) {
  __shared__ int lh[NREL];
  __shared__ int lc[NREL];
  __shared__ int goff[NREL];
  __shared__ int ls[128];
  __shared__ int es_l[EPB];
  __shared__ int tp_l[EPB];
  __shared__ int dst_l[EPB];
  int tid = threadIdx.x, blk = blockIdx.x;
  int base = blk * EPB;
  int nv = NEDGES - base; if (nv > EPB) nv = EPB;
  if (tid < NREL) {
    lh[tid] = 0; lc[tid] = 0;
    goff[tid] = hist[tid * NBH + blk];
  }
  __syncthreads();
  int r4[4], s4[4], t4[4];
#pragma unroll
  for (int k = 0; k < 4; ++k) {
    int j = tid + k * 1024;
    if (j < nv) {
      int i = base + j;
      r4[k] = rel[i]; s4[k] = src[i]; t4[k] = tgt[i];
      atomicAdd(&lh[r4[k]], 1);
    } else r4[k] = -1;
  }
  __syncthreads();
  if (tid < 128) ls[tid] = (tid < NREL) ? lh[tid] : 0;
  __syncthreads();
  for (int d = 1; d < 128; d <<= 1) {
    int t = 0;
    if (tid < 128 && tid >= d) t = ls[tid - d];
    __syncthreads();
    if (tid < 128) ls[tid] += t;
    __syncthreads();
  }
#pragma unroll
  for (int k = 0; k < 4; ++k) {
    if (r4[k] >= 0) {
      int r = r4[k];
      int rank = atomicAdd(&lc[r], 1);
      int lpos = ls[r] - lh[r] + rank;
      es_l[lpos] = s4[k];
      dst_l[lpos] = goff[r] + rank;
      tp_l[lpos] = row_ptr[t4[k]] + atomicAdd(&fill_t[t4[k]], 1);
    }
  }
  __syncthreads();
  for (int j = tid; j < nv; j += 1024) {
    int d = dst_l[j];
    es[d] = es_l[j];
    tp[d] = tp_l[j];
  }
}

// ---------- entity-level exclusive scan of indegree (CSR row_ptr) ----------
__global__ void k_escanA(const int* __restrict__ indeg, int* __restrict__ loc,
                         int* __restrict__ bsum) {
  __shared__ int s[256];
  int tid = threadIdx.x;
  int base = blockIdx.x * 1024 + tid * 4;
  int v0 = (base + 0 < NENT) ? indeg[base + 0] : 0;
  int v1 = (base + 1 < NENT) ? indeg[base + 1] : 0;
  int v2 = (base + 2 < NENT) ? indeg[base + 2] : 0;
  int v3 = (base + 3 < NENT) ? indeg[base + 3] : 0;
  s[tid] = v0 + v1 + v2 + v3;
  __syncthreads();
  for (int d = 1; d < 256; d <<= 1) {
    int t = (tid >= d) ? s[tid - d] : 0;
    __syncthreads();
    s[tid] += t;
    __syncthreads();
  }
  int off = (tid > 0) ? s[tid - 1] : 0;
  if (base + 0 < NENT) loc[base + 0] = off;
  if (base + 1 < NENT) loc[base + 1] = off + v0;
  if (base + 2 < NENT) loc[base + 2] = off + v0 + v1;
  if (base + 3 < NENT) loc[base + 3] = off + v0 + v1 + v2;
  if (tid == 255) bsum[blockIdx.x] = s[255];
}

// row_ptr: each block redundantly scans the 98 block sums (escanB folded in)
__global__ void k_escanC(const int* __restrict__ loc, const int* __restrict__ bsum,
                         int* __restrict__ row_ptr) {
  __shared__ int sb[128];
  int tid = threadIdx.x;
  if (tid < 128) sb[tid] = (tid < NB_ESCAN) ? bsum[tid] : 0;
  __syncthreads();
  for (int d = 1; d < 128; d <<= 1) {
    int t = 0;
    if (tid < 128 && tid >= d) t = sb[tid - d];
    __syncthreads();
    if (tid < 128) sb[tid] += t;
    __syncthreads();
  }
  int i = blockIdx.x * 256 + tid;
  if (i < NENT) {
    int b = i >> 10;
    row_ptr[i] = loc[i] + (b > 0 ? sb[b - 1] : 0);
  }
}

// ---------- x fp32 -> bf16, pre-swizzled rows (chunk g holds logical chunk g^(row&7)) ----------
__global__ void k_tobf(const float* __restrict__ x, u16* __restrict__ xbf) {
  int t = blockIdx.x * 256 + threadIdx.x;   // row*16 + g
  int row = t >> 4, g = t & 15;
  int c = g ^ (row & 7);
  const float4* xr = (const float4*)(x + (size_t)row * DIM + c * 8);
  float4 a = xr[0], b = xr[1];
  uint4 o;
  o.x = pk2(a.x, a.y); o.y = pk2(a.z, a.w);
  o.z = pk2(b.x, b.y); o.w = pk2(b.z, b.w);
  *(uint4*)(xbf + (size_t)row * DIM + g * 8) = o;
}

// ---------- Wt[r][dim][k] = sum_b coef*bases[b][k][dim], bf16, pre-swizzled ----------
__global__ void k_wmatT(const float* __restrict__ bases, const float* __restrict__ coefs_l,
                        u16* __restrict__ Wt) {
  int g = blockIdx.x * 256 + threadIdx.x;   // r*2048 + k8*128 + dim
  int r = g >> 11;
  int rem = g & 2047;
  int k8 = rem >> 7;
  int dim = rem & 127;
  float cf[NBASES];
#pragma unroll
  for (int bb = 0; bb < NBASES; ++bb) cf[bb] = coefs_l[r * NBASES + bb];
  float v[8];
#pragma unroll
  for (int i = 0; i < 8; ++i) v[i] = 0.f;
  for (int bb = 0; bb < NBASES; ++bb) {
    const float* bp = bases + (size_t)bb * DIM * DIM + (k8 * 8) * DIM + dim;
#pragma unroll
    for (int i = 0; i < 8; ++i) v[i] += cf[bb] * bp[i * DIM];
  }
  uint4 o;
  o.x = pk2(v[0], v[1]); o.y = pk2(v[2], v[3]);
  o.z = pk2(v[4], v[5]); o.w = pk2(v[6], v[7]);
  *(uint4*)(Wt + (size_t)r * DIM * DIM + dim * DIM + ((k8 ^ (dim & 7)) * 8)) = o;
}

// ---------- self_w transposed bf16 swizzled (both layers) ----------
__global__ void k_swtT(const float* __restrict__ sw, u16* __restrict__ swt) {
  int g = blockIdx.x * 256 + threadIdx.x;   // l*2048 + k8*128 + dim
  int ll = g >> 11;
  int rem = g & 2047;
  int k8 = rem >> 7;
  int dim = rem & 127;
  const float* bp = sw + (size_t)ll * DIM * DIM + (k8 * 8) * DIM + dim;
  float v[8];
#pragma unroll
  for (int i = 0; i < 8; ++i) v[i] = bp[i * DIM];
  uint4 o;
  o.x = pk2(v[0], v[1]); o.y = pk2(v[2], v[3]);
  o.z = pk2(v[4], v[5]); o.w = pk2(v[6], v[7]);
  *(uint4*)(swt + (size_t)ll * DIM * DIM + dim * DIM + ((k8 ^ (dim & 7)) * 8)) = o;
}

// ---------- persistent edge kernel: 4-wave blocks, CH=64, 3 blocks/CU ----------
__launch_bounds__(256, 3)
__global__ void k_edgeP(const u16* __restrict__ xbf, const u16* __restrict__ Wt,
                        const int* __restrict__ es, const int* __restrict__ tp,
                        const int* __restrict__ chunk_rel, const int* __restrict__ chunk_start,
                        const int* __restrict__ chunk_valid, const int* __restrict__ chunkT,
                        u16* __restrict__ msg) {
  __shared__ __align__(16) char smem[49152];   // [0,32K): Wt  [32K,48K): xs (64 rows)
  int nch = *chunkT;
  int K = (nch + NPERS - 1) / NPERS;
  int c0 = blockIdx.x * K;
  int c1 = c0 + K; if (c1 > nch) c1 = nch;
  if (c0 >= nch) return;
  int tid = threadIdx.x;
  int w = tid >> 6, l = tid & 63;   // w == dt (4 waves)
  int lr = l & 31, hi = l >> 5;
  int d = w * 32 + lr;
  int aswz = d & 7, bswz = lr & 7;  // (lr+32)&7 == lr&7
  const char* wb = smem;
  const char* xb = smem + 32768;
  int curR = -1;
  for (int cb = c0; cb < c1; ++cb) {
    int r = chunk_rel[cb], base = chunk_start[cb], nv = chunk_valid[cb];
    __syncthreads();   // all waves done reading previous LDS contents
    if (r != curR) {
      const char* wg = (const char*)(Wt + (size_t)r * DIM * DIM);
#pragma unroll
      for (int it = 0; it < 8; ++it) {
        int off = it * 4096 + tid * 16;
        GLD16(wg + off, smem + off);
      }
      curR = r;
    }
    {
      int e = tid >> 2, q = tid & 3;   // 64 rows x 4 threads
      int sidx = (e < nv) ? es[base + e] : 0;
      const char* xr = (const char*)(xbf + (size_t)sidx * DIM);
      char* xd = smem + 32768 + e * 256;
      int xk = (sidx & 7) ^ (e & 7);
#pragma unroll
      for (int i = 0; i < 4; ++i) {
        int g = q * 4 + i;
        uint4 v = *(const uint4*)(xr + g * 16);
        *(uint4*)(xd + ((g ^ xk) * 16)) = v;
      }
    }
    // prefetch tp for this chunk's stores (in flight during the barrier drain)
    int pA = (lr < nv) ? tp[base + lr] : 0;
    int pB = (lr + 32 < nv) ? tp[base + lr + 32] : 0;
    __syncthreads();   // staging (GLD16 + ds_write) complete
    f32x16 accA, accB;
#pragma unroll
    for (int i = 0; i < 16; ++i) { accA[i] = 0.f; accB[i] = 0.f; }
#pragma unroll
    for (int s = 0; s < 8; ++s) {
      int c = s * 2 + hi;
      bf16x8 av = *(const bf16x8*)(wb + d * 256 + ((c ^ aswz) * 16));
      bf16x8 b1 = *(const bf16x8*)(xb + lr * 256 + ((c ^ bswz) * 16));
      bf16x8 b2 = *(const bf16x8*)(xb + (lr + 32) * 256 + ((c ^ bswz) * 16));
      accA = __builtin_amdgcn_mfma_f32_32x32x16_bf16(av, b1, accA, 0, 0, 0);
      accB = __builtin_amdgcn_mfma_f32_32x32x16_bf16(av, b2, accB, 0, 0, 0);
    }
    // msg row layout: [dt(4)][hi(2)][16 vals] — lane's 16 values contiguous (32B)
#pragma unroll
    for (int t = 0; t < 2; ++t) {
      int e = lr + t * 32;
      if (e < nv) {
        int p = t ? pB : pA;
        u16* mrow = msg + (size_t)p * DIM + w * 32 + hi * 16;
#pragma unroll
        for (int half = 0; half < 2; ++half) {
          float v0 = t ? accB[8 * half + 0] : accA[8 * half + 0];
          float v1 = t ? accB[8 * half + 1] : accA[8 * half + 1];
          float v2 = t ? accB[8 * half + 2] : accA[8 * half + 2];
          float v3 = t ? accB[8 * half + 3] : accA[8 * half + 3];
          float v4 = t ? accB[8 * half + 4] : accA[8 * half + 4];
          float v5 = t ? accB[8 * half + 5] : accA[8 * half + 5];
          float v6 = t ? accB[8 * half + 6] : accA[8 * half + 6];
          float v7 = t ? accB[8 * half + 7] : accA[8 * half + 7];
          uint4 o;
          o.x = pk2(v0, v1); o.y = pk2(v2, v3);
          o.z = pk2(v4, v5); o.w = pk2(v6, v7);
          *(uint4*)(mrow + 8 * half) = o;
        }
      }
    }
  }
}

// ---------- combine: relu(segsum(msg)*inv + x@self_w + bias) via MFMA ----------
#define ACC8(M, B_) \
  ms[(B_) + 0] += bf2f((M).x & 0xffffu); ms[(B_) + 1] += bf2f((M).x >> 16); \
  ms[(B_) + 2] += bf2f((M).y & 0xffffu); ms[(B_) + 3] += bf2f((M).y >> 16); \
  ms[(B_) + 4] += bf2f((M).z & 0xffffu); ms[(B_) + 5] += bf2f((M).z >> 16); \
  ms[(B_) + 6] += bf2f((M).w & 0xffffu); ms[(B_) + 7] += bf2f((M).w >> 16);

__launch_bounds__(512, 4)
__global__ void k_combM(const u16* __restrict__ xbf, const u16* __restrict__ swt,
                        const float* __restrict__ bias_l, const u16* __restrict__ msg,
                        const int* __restrict__ row_ptr, const int* __restrict__ indeg,
                        float* __restrict__ outf, u16* __restrict__ outb, int last) {
  __shared__ __align__(16) char smem[65536];
  int tid = threadIdx.x;
  int r0 = blockIdx.x * 128;
  {
    const char* wg = (const char*)swt;
    const char* xg = (const char*)(xbf + (size_t)r0 * DIM);
#pragma unroll
    for (int it = 0; it < 4; ++it) {
      int off = it * 8192 + tid * 16;
      GLD16(wg + off, smem + off);
      GLD16(xg + off, smem + 32768 + off);
    }
  }
  __syncthreads();
  int w = tid >> 6, l = tid & 63;
  int lr = l & 31, hi = l >> 5;
  int dt = w & 3;
  int d = dt * 32 + lr;
  int e1 = (w >> 2) * 32 + lr;
  const char* wb = smem;
  const char* xb = smem + 32768;
  f32x16 accA, accB;
#pragma unroll
  for (int i = 0; i < 16; ++i) { accA[i] = 0.f; accB[i] = 0.f; }
  int aswz = d & 7, bswz = lr & 7;
#pragma unroll
  for (int s = 0; s < 8; ++s) {
    int c = s * 2 + hi;
    bf16x8 av = *(const bf16x8*)(wb + d * 256 + ((c ^ aswz) * 16));
    bf16x8 b1 = *(const bf16x8*)(xb + e1 * 256 + ((c ^ bswz) * 16));
    bf16x8 b2 = *(const bf16x8*)(xb + (e1 + 64) * 256 + ((c ^ bswz) * 16));
    accA = __builtin_amdgcn_mfma_f32_32x32x16_bf16(av, b1, accA, 0, 0, 0);
    accB = __builtin_amdgcn_mfma_f32_32x32x16_bf16(av, b2, accB, 0, 0, 0);
  }
#pragma unroll
  for (int t = 0; t < 2; ++t) {
    int ent = r0 + e1 + t * 64;
    int vald = (ent < NENT);
    int eb = vald ? row_ptr[ent] : 0;
    int dg = vald ? indeg[ent] : 0;
    float inv = 1.f / (float)(dg > 1 ? dg : 1);
    float ms[16];
#pragma unroll
    for (int i = 0; i < 16; ++i) ms[i] = 0.f;
    const u16* mp = msg + (size_t)eb * DIM + dt * 32 + hi * 16;
    int j = 0;
    for (; j + 1 < dg; j += 2) {
      uint4 m1 = *(const uint4*)(mp);
      uint4 m2 = *(const uint4*)(mp + 8);
      uint4 m3 = *(const uint4*)(mp + DIM);
      uint4 m4 = *(const uint4*)(mp + DIM + 8);
      ACC8(m1, 0) ACC8(m2, 8) ACC8(m3, 0) ACC8(m4, 8)
      mp += 2 * DIM;
    }
    if (j < dg) {
      uint4 m1 = *(const uint4*)(mp);
      uint4 m2 = *(const uint4*)(mp + 8);
      ACC8(m1, 0) ACC8(m2, 8)
    }
    if (vald) {
#pragma unroll
      for (int q = 0; q < 4; ++q) {
        float4 bi = *(const float4*)(bias_l + dt * 32 + hi * 4 + 8 * q);
        float a0 = t ? accB[4 * q + 0] : accA[4 * q + 0];
        float a1 = t ? accB[4 * q + 1] : accA[4 * q + 1];
        float a2 = t ? accB[4 * q + 2] : accA[4 * q + 2];
        float a3 = t ? accB[4 * q + 3] : accA[4 * q + 3];
        float o0 = fmaxf(ms[4 * q + 0] * inv + a0 + bi.x, 0.f);
        float o1 = fmaxf(ms[4 * q + 1] * inv + a1 + bi.y, 0.f);
        float o2 = fmaxf(ms[4 * q + 2] * inv + a2 + bi.z, 0.f);
        float o3 = fmaxf(ms[4 * q + 3] * inv + a3 + bi.w, 0.f);
        if (last) {
          float4 o = make_float4(o0, o1, o2, o3);
          *(float4*)(outf + (size_t)ent * DIM + dt * 32 + hi * 4 + 8 * q) = o;
        } else {
          int c16 = 4 * dt + q;
          uint2 o;
          o.x = pk2(o0, o1); o.y = pk2(o2, o3);
          *(uint2*)(outb + (size_t)ent * DIM + ((c16 ^ (ent & 7)) * 8) + 4 * hi) = o;
        }
      }
    }
  }
}

extern "C" void kernel_launch(void* const* d_in, const int* in_sizes, int n_in,
                              void* d_out, int out_size, void* d_ws, size_t ws_size,
                              hipStream_t stream) {
  const float* x0    = (const float*)d_in[0];
  const float* bases = (const float*)d_in[1];
  const float* coefs = (const float*)d_in[2];
  const float* selfw = (const float*)d_in[3];
  const float* bias  = (const float*)d_in[4];
  const int* src = (const int*)d_in[5];
  const int* tgt = (const int*)d_in[6];
  const int* rel = (const int*)d_in[7];
  float* out = (float*)d_out;

  char* ws = (char*)d_ws;
  size_t off = 0;
  auto alloc = [&](size_t bytes) -> void* {
    void* p = ws + off;
    off = (off + bytes + 255) & ~(size_t)255;
    return p;
  };
  u16* Wt   = (u16*)alloc((size_t)NREL * DIM * DIM * 2);      // 3.3 MB
  u16* swt  = (u16*)alloc((size_t)2 * DIM * DIM * 2);         // 64 KB
  u16* xbf  = (u16*)alloc((size_t)NENTPAD * DIM * 2);         // 25.6 MB
  u16* msg  = (u16*)alloc((size_t)NEDGES * DIM * 2);          // 153.6 MB
  int* es      = (int*)alloc((size_t)PADE * sizeof(int));
  int* tp      = (int*)alloc((size_t)PADE * sizeof(int));
  int* indeg   = (int*)alloc((size_t)NENT * sizeof(int));
  int* row_ptr = (int*)alloc((size_t)NENT * sizeof(int));
  int* loc     = (int*)alloc((size_t)NENT * sizeof(int));
  int* fill_t  = (int*)alloc((size_t)NENT * sizeof(int));
  int* bsum    = (int*)alloc(128 * sizeof(int));
  int* hist    = (int*)alloc((size_t)NREL * NBH * sizeof(int));
  int* chunk_rel   = (int*)alloc(TMAX * sizeof(int));
  int* chunk_start = (int*)alloc(TMAX * sizeof(int));
  int* chunk_valid = (int*)alloc(TMAX * sizeof(int));
  int* chunkT      = (int*)alloc(sizeof(int));

  hipMemsetAsync(indeg, 0, (size_t)NENT * sizeof(int), stream);
  hipMemsetAsync(fill_t, 0, (size_t)NENT * sizeof(int), stream);

  k_hist2<<<NBH, 1024, 0, stream>>>(tgt, rel, indeg, hist);
  k_scan2<<<1, 1024, 0, stream>>>(hist, chunk_rel, chunk_start, chunk_valid, chunkT);
  k_escanA<<<NB_ESCAN, 256, 0, stream>>>(indeg, loc, bsum);
  k_escanC<<<(NENT + 255) / 256, 256, 0, stream>>>(loc, bsum, row_ptr);
  k_scatter2<<<NBH, 1024, 0, stream>>>(src, tgt, rel, hist, row_ptr, fill_t, es, tp);
  k_tobf<<<(NENT * 16) / 256, 256, 0, stream>>>(x0, xbf);
  k_swtT<<<16, 256, 0, stream>>>(selfw, swt);

  for (int l = 0; l < 2; ++l) {
    k_wmatT<<<(NREL * 2048) / 256, 256, 0, stream>>>(bases, coefs + l * NREL * NBASES, Wt);
    k_edgeP<<<NPERS, 256, 0, stream>>>(xbf, Wt, es, tp,
                                       chunk_rel, chunk_start, chunk_valid, chunkT, msg);
    k_combM<<<NENTPAD / 128, 512, 0, stream>>>(xbf, swt + (size_t)l * DIM * DIM,
                                               bias + l * DIM, msg, row_ptr, indeg,
                                               out, xbf, l == 0 ? 0 : 1);
  }
}

// Round 14
// 322.183 us; speedup vs baseline: 1.0192x; 1.0192x over previous
//
#include <hip/hip_runtime.h>

#define NENT    100000
#define NENTPAD 100096      // 782*128, padded for combine staging
#define NREL    100
#define DIM     128
#define NBASES  10
#define NEDGES  600000
#define CH      128
#define TMAX    4788
#define PADE    612736
#define NB_ESCAN 98
#define EPB     4096        // edges per sort block
#define NBH     147         // ceil(NEDGES/EPB)
#define NPERS   512         // persistent edge-kernel grid (2 blocks/CU)

typedef unsigned short u16;
typedef unsigned int   u32;
typedef __bf16  bf16x8 __attribute__((ext_vector_type(8)));
typedef float   f32x16 __attribute__((ext_vector_type(16)));

static __device__ __forceinline__ u16 f2bf(float f) {
  u32 u = __float_as_uint(f);
  u = (u + 0x7fffu + ((u >> 16) & 1u)) >> 16;
  return (u16)u;
}
static __device__ __forceinline__ float bf2f(u32 h) {
  return __uint_as_float(h << 16);
}
static __device__ __forceinline__ u32 pk2(float a, float b) {
  return (u32)f2bf(a) | ((u32)f2bf(b) << 16);
}
#define GLD16(g, l) __builtin_amdgcn_global_load_lds( \
    (__attribute__((address_space(1))) u32*)(g), \
    (__attribute__((address_space(3))) u32*)(l), 16, 0, 0)

// ---------- phase 1: per-block relation histogram + indegree ----------
__global__ __launch_bounds__(1024) void k_hist2(const int* __restrict__ tgt,
                                                const int* __restrict__ rel,
                                                int* __restrict__ indeg,
                                                int* __restrict__ hist) {
  __shared__ int h[NREL];
  int tid = threadIdx.x, blk = blockIdx.x;
  if (tid < NREL) h[tid] = 0;
  __syncthreads();
  int base = blk * EPB;
  int nv = NEDGES - base; if (nv > EPB) nv = EPB;
#pragma unroll
  for (int k = 0; k < 4; ++k) {
    int j = tid + k * 1024;
    if (j < nv) {
      int i = base + j;
      atomicAdd(&indeg[tgt[i]], 1);
      atomicAdd(&h[rel[i]], 1);
    }
  }
  __syncthreads();
  if (tid < NREL) hist[tid * NBH + blk] = h[tid];
}

// ---------- phase 2: chunk table + absolute per-(rel,block) offsets ----------
__global__ __launch_bounds__(1024) void k_scan2(int* __restrict__ hist,
                                                int* __restrict__ chunk_rel,
                                                int* __restrict__ chunk_start,
                                                int* __restrict__ chunk_valid,
                                                int* __restrict__ chunkT) {
  __shared__ int sh[NREL * NBH];   // 57.4 KB
  __shared__ int cnt[NREL];
  __shared__ int cb[128];
  int tid = threadIdx.x;
  for (int i = tid; i < NREL * NBH; i += 1024) sh[i] = hist[i];
  __syncthreads();
  if (tid < NREL) {
    int s = 0;
    for (int b = 0; b < NBH; ++b) s += sh[tid * NBH + b];
    cnt[tid] = s;
  }
  __syncthreads();
  if (tid < 128) cb[tid] = (tid < NREL) ? (cnt[tid] + CH - 1) / CH : 0;
  __syncthreads();
  for (int d = 1; d < 128; d <<= 1) {
    int t = 0;
    if (tid < 128 && tid >= d) t = cb[tid - d];
    __syncthreads();
    if (tid < 128) cb[tid] += t;
    __syncthreads();
  }
  if (tid < NREL) {
    int c = cnt[tid];
    int nch = (c + CH - 1) / CH;
    int cb0 = cb[tid] - nch;
    int poff = cb0 * CH;
    for (int i = 0; i < nch; ++i) {
      chunk_rel[cb0 + i] = tid;
      chunk_start[cb0 + i] = (cb0 + i) * CH;
      int v = c - i * CH;
      if (v > CH) v = CH;
      chunk_valid[cb0 + i] = v;
    }
    int run = poff;
    for (int b = 0; b < NBH; ++b) {
      int t = sh[tid * NBH + b];
      sh[tid * NBH + b] = run;
      run += t;
    }
  }
  if (tid == 127) *chunkT = cb[127];
  __syncthreads();
  for (int i = tid; i < NREL * NBH; i += 1024) hist[i] = sh[i];
}

// ---------- phase 3: staged, relation-grouped scatter (coalesced writes) ----------
__global__ __launch_bounds__(1024) void k_scatter2(const int* __restrict__ src,
                                                   const int* __restrict__ tgt,
                                                   const int* __restrict__ rel,
                                                   const int* __restrict__ hist,
                                                   const int* __restrict__ row_ptr,
                                                   int* __restrict__ fill_t,
                                                   int* __restrict__ es,
                                                   int* __restrict__ tp) {
  __shared__ int lh[NREL];
  __shared__ int lc[NREL];
  __shared__ int goff[NREL];
  __shared__ int ls[128];
  __shared__ int es_l[EPB];
  __shared__ int tp_l[EPB];
  __shared__ int dst_l[EPB];
  int tid = threadIdx.x, blk = blockIdx.x;
  int base = blk * EPB;
  int nv = NEDGES - base; if (nv > EPB) nv = EPB;
  if (tid < NREL) {
    lh[tid] = 0; lc[tid] = 0;
    goff[tid] = hist[tid * NBH + blk];
  }
  __syncthreads();
  int r4[4], s4[4], t4[4];
#pragma unroll
  for (int k = 0; k < 4; ++k) {
    int j = tid + k * 1024;
    if (j < nv) {
      int i = base + j;
      r4[k] = rel[i]; s4[k] = src[i]; t4[k] = tgt[i];
      atomicAdd(&lh[r4[k]], 1);
    } else r4[k] = -1;
  }
  __syncthreads();
  if (tid < 128) ls[tid] = (tid < NREL) ? lh[tid] : 0;
  __syncthreads();
  for (int d = 1; d < 128; d <<= 1) {
    int t = 0;
    if (tid < 128 && tid >= d) t = ls[tid - d];
    __syncthreads();
    if (tid < 128) ls[tid] += t;
    __syncthreads();
  }
#pragma unroll
  for (int k = 0; k < 4; ++k) {
    if (r4[k] >= 0) {
      int r = r4[k];
      int rank = atomicAdd(&lc[r], 1);
      int lpos = ls[r] - lh[r] + rank;
      es_l[lpos] = s4[k];
      dst_l[lpos] = goff[r] + rank;
      tp_l[lpos] = row_ptr[t4[k]] + atomicAdd(&fill_t[t4[k]], 1);
    }
  }
  __syncthreads();
  for (int j = tid; j < nv; j += 1024) {
    int d = dst_l[j];
    es[d] = es_l[j];
    tp[d] = tp_l[j];
  }
}

// ---------- entity-level exclusive scan of indegree (CSR row_ptr) ----------
__global__ void k_escanA(const int* __restrict__ indeg, int* __restrict__ loc,
                         int* __restrict__ bsum) {
  __shared__ int s[256];
  int tid = threadIdx.x;
  int base = blockIdx.x * 1024 + tid * 4;
  int v0 = (base + 0 < NENT) ? indeg[base + 0] : 0;
  int v1 = (base + 1 < NENT) ? indeg[base + 1] : 0;
  int v2 = (base + 2 < NENT) ? indeg[base + 2] : 0;
  int v3 = (base + 3 < NENT) ? indeg[base + 3] : 0;
  s[tid] = v0 + v1 + v2 + v3;
  __syncthreads();
  for (int d = 1; d < 256; d <<= 1) {
    int t = (tid >= d) ? s[tid - d] : 0;
    __syncthreads();
    s[tid] += t;
    __syncthreads();
  }
  int off = (tid > 0) ? s[tid - 1] : 0;
  if (base + 0 < NENT) loc[base + 0] = off;
  if (base + 1 < NENT) loc[base + 1] = off + v0;
  if (base + 2 < NENT) loc[base + 2] = off + v0 + v1;
  if (base + 3 < NENT) loc[base + 3] = off + v0 + v1 + v2;
  if (tid == 255) bsum[blockIdx.x] = s[255];
}

// row_ptr: each block redundantly scans the 98 block sums (escanB folded in)
__global__ void k_escanC(const int* __restrict__ loc, const int* __restrict__ bsum,
                         int* __restrict__ row_ptr) {
  __shared__ int sb[128];
  int tid = threadIdx.x;
  if (tid < 128) sb[tid] = (tid < NB_ESCAN) ? bsum[tid] : 0;
  __syncthreads();
  for (int d = 1; d < 128; d <<= 1) {
    int t = 0;
    if (tid < 128 && tid >= d) t = sb[tid - d];
    __syncthreads();
    if (tid < 128) sb[tid] += t;
    __syncthreads();
  }
  int i = blockIdx.x * 256 + tid;
  if (i < NENT) {
    int b = i >> 10;
    row_ptr[i] = loc[i] + (b > 0 ? sb[b - 1] : 0);
  }
}

// ---------- x fp32 -> bf16, pre-swizzled rows (chunk g holds logical chunk g^(row&7)) ----------
__global__ void k_tobf(const float* __restrict__ x, u16* __restrict__ xbf) {
  int t = blockIdx.x * 256 + threadIdx.x;   // row*16 + g
  int row = t >> 4, g = t & 15;
  int c = g ^ (row & 7);
  const float4* xr = (const float4*)(x + (size_t)row * DIM + c * 8);
  float4 a = xr[0], b = xr[1];
  uint4 o;
  o.x = pk2(a.x, a.y); o.y = pk2(a.z, a.w);
  o.z = pk2(b.x, b.y); o.w = pk2(b.z, b.w);
  *(uint4*)(xbf + (size_t)row * DIM + g * 8) = o;
}

// ---------- Wt[r][dim][k] = sum_b coef*bases[b][k][dim], bf16, pre-swizzled ----------
__global__ void k_wmatT(const float* __restrict__ bases, const float* __restrict__ coefs_l,
                        u16* __restrict__ Wt) {
  int g = blockIdx.x * 256 + threadIdx.x;   // r*2048 + k8*128 + dim
  int r = g >> 11;
  int rem = g & 2047;
  int k8 = rem >> 7;
  int dim = rem & 127;
  float cf[NBASES];
#pragma unroll
  for (int bb = 0; bb < NBASES; ++bb) cf[bb] = coefs_l[r * NBASES + bb];
  float v[8];
#pragma unroll
  for (int i = 0; i < 8; ++i) v[i] = 0.f;
  for (int bb = 0; bb < NBASES; ++bb) {
    const float* bp = bases + (size_t)bb * DIM * DIM + (k8 * 8) * DIM + dim;
#pragma unroll
    for (int i = 0; i < 8; ++i) v[i] += cf[bb] * bp[i * DIM];
  }
  uint4 o;
  o.x = pk2(v[0], v[1]); o.y = pk2(v[2], v[3]);
  o.z = pk2(v[4], v[5]); o.w = pk2(v[6], v[7]);
  *(uint4*)(Wt + (size_t)r * DIM * DIM + dim * DIM + ((k8 ^ (dim & 7)) * 8)) = o;
}

// ---------- self_w transposed bf16 swizzled (both layers) ----------
__global__ void k_swtT(const float* __restrict__ sw, u16* __restrict__ swt) {
  int g = blockIdx.x * 256 + threadIdx.x;   // l*2048 + k8*128 + dim
  int ll = g >> 11;
  int rem = g & 2047;
  int k8 = rem >> 7;
  int dim = rem & 127;
  const float* bp = sw + (size_t)ll * DIM * DIM + (k8 * 8) * DIM + dim;
  float v[8];
#pragma unroll
  for (int i = 0; i < 8; ++i) v[i] = bp[i * DIM];
  uint4 o;
  o.x = pk2(v[0], v[1]); o.y = pk2(v[2], v[3]);
  o.z = pk2(v[4], v[5]); o.w = pk2(v[6], v[7]);
  *(uint4*)(swt + (size_t)ll * DIM * DIM + dim * DIM + ((k8 ^ (dim & 7)) * 8)) = o;
}

// ---------- persistent edge kernel with async-STAGE split (T14) ----------
__launch_bounds__(512, 2)
__global__ void k_edgeP(const u16* __restrict__ xbf, const u16* __restrict__ Wt,
                        const int* __restrict__ es, const int* __restrict__ tp,
                        const int* __restrict__ chunk_rel, const int* __restrict__ chunk_start,
                        const int* __restrict__ chunk_valid, const int* __restrict__ chunkT,
                        u16* __restrict__ msg) {
  __shared__ __align__(16) char smem[65536];   // [0,32K): Wt  [32K,64K): xs
  int nch = *chunkT;
  int K = (nch + NPERS - 1) / NPERS;
  int c0 = blockIdx.x * K;
  int c1 = c0 + K; if (c1 > nch) c1 = nch;
  if (c0 >= nch) return;
  int tid = threadIdx.x;
  int w = tid >> 6, l = tid & 63;
  int lr = l & 31, hi = l >> 5;
  int dt = w & 3;
  int d = dt * 32 + lr;
  int e1 = (w >> 2) * 32 + lr;
  int aswz = d & 7, bswz = lr & 7;
  const char* wb = smem;
  const char* xb = smem + 32768;
  int eS = tid >> 2, q = tid & 3;   // staging: 128 rows x 4 threads
  char* xd = smem + 32768 + eS * 256;
  int curR = -1;
  // ---- prologue: load + stage chunk c0 ----
  int nbase = chunk_start[c0], nnv = chunk_valid[c0], nrel = chunk_rel[c0];
  uint4 vr0, vr1, vr2, vr3;
  int xk;
  {
    int sidx = (eS < nnv) ? es[nbase + eS] : 0;
    const char* xr = (const char*)(xbf + (size_t)sidx * DIM);
    vr0 = *(const uint4*)(xr + (q * 4 + 0) * 16);
    vr1 = *(const uint4*)(xr + (q * 4 + 1) * 16);
    vr2 = *(const uint4*)(xr + (q * 4 + 2) * 16);
    vr3 = *(const uint4*)(xr + (q * 4 + 3) * 16);
    xk = (sidx & 7) ^ (eS & 7);
  }
  {
    const char* wg = (const char*)(Wt + (size_t)nrel * DIM * DIM);
#pragma unroll
    for (int it = 0; it < 4; ++it) {
      int off = it * 8192 + tid * 16;
      GLD16(wg + off, smem + off);
    }
    curR = nrel;
  }
  *(uint4*)(xd + (((q * 4 + 0) ^ xk) * 16)) = vr0;
  *(uint4*)(xd + (((q * 4 + 1) ^ xk) * 16)) = vr1;
  *(uint4*)(xd + (((q * 4 + 2) ^ xk) * 16)) = vr2;
  *(uint4*)(xd + (((q * 4 + 3) ^ xk) * 16)) = vr3;
  __syncthreads();

  for (int cb = c0; cb < c1; ++cb) {
    int base = nbase, nv = nnv;
    int havenext = (cb + 1 < c1);
    // issue NEXT chunk's gather early (latency hides under compute)
    if (havenext) {
      nbase = chunk_start[cb + 1]; nnv = chunk_valid[cb + 1]; nrel = chunk_rel[cb + 1];
      int sidx = (eS < nnv) ? es[nbase + eS] : 0;
      const char* xr = (const char*)(xbf + (size_t)sidx * DIM);
      vr0 = *(const uint4*)(xr + (q * 4 + 0) * 16);
      vr1 = *(const uint4*)(xr + (q * 4 + 1) * 16);
      vr2 = *(const uint4*)(xr + (q * 4 + 2) * 16);
      vr3 = *(const uint4*)(xr + (q * 4 + 3) * 16);
      xk = (sidx & 7) ^ (eS & 7);
    }
    // prefetch current tp
    int pA = (e1 < nv) ? tp[base + e1] : 0;
    int pB = (e1 + 64 < nv) ? tp[base + e1 + 64] : 0;
    // compute current chunk
    f32x16 accA, accB;
#pragma unroll
    for (int i = 0; i < 16; ++i) { accA[i] = 0.f; accB[i] = 0.f; }
#pragma unroll
    for (int s = 0; s < 8; ++s) {
      int c = s * 2 + hi;
      bf16x8 av = *(const bf16x8*)(wb + d * 256 + ((c ^ aswz) * 16));
      bf16x8 b1 = *(const bf16x8*)(xb + e1 * 256 + ((c ^ bswz) * 16));
      bf16x8 b2 = *(const bf16x8*)(xb + (e1 + 64) * 256 + ((c ^ bswz) * 16));
      accA = __builtin_amdgcn_mfma_f32_32x32x16_bf16(av, b1, accA, 0, 0, 0);
      accB = __builtin_amdgcn_mfma_f32_32x32x16_bf16(av, b2, accB, 0, 0, 0);
    }
    // msg row layout: [dt(4)][hi(2)][16 vals]
#pragma unroll
    for (int t = 0; t < 2; ++t) {
      int e = e1 + t * 64;
      if (e < nv) {
        int p = t ? pB : pA;
        u16* mrow = msg + (size_t)p * DIM + dt * 32 + hi * 16;
#pragma unroll
        for (int half = 0; half < 2; ++half) {
          float v0 = t ? accB[8 * half + 0] : accA[8 * half + 0];
          float v1 = t ? accB[8 * half + 1] : accA[8 * half + 1];
          float v2 = t ? accB[8 * half + 2] : accA[8 * half + 2];
          float v3 = t ? accB[8 * half + 3] : accA[8 * half + 3];
          float v4 = t ? accB[8 * half + 4] : accA[8 * half + 4];
          float v5 = t ? accB[8 * half + 5] : accA[8 * half + 5];
          float v6 = t ? accB[8 * half + 6] : accA[8 * half + 6];
          float v7 = t ? accB[8 * half + 7] : accA[8 * half + 7];
          uint4 o;
          o.x = pk2(v0, v1); o.y = pk2(v2, v3);
          o.z = pk2(v4, v5); o.w = pk2(v6, v7);
          *(uint4*)(mrow + 8 * half) = o;
        }
      }
    }
    __syncthreads();   // all waves done reading xs[cb] (and W if changing)
    if (havenext) {
      if (nrel != curR) {
        const char* wg = (const char*)(Wt + (size_t)nrel * DIM * DIM);
#pragma unroll
        for (int it = 0; it < 4; ++it) {
          int off = it * 8192 + tid * 16;
          GLD16(wg + off, smem + off);
        }
        curR = nrel;
      }
      *(uint4*)(xd + (((q * 4 + 0) ^ xk) * 16)) = vr0;
      *(uint4*)(xd + (((q * 4 + 1) ^ xk) * 16)) = vr1;
      *(uint4*)(xd + (((q * 4 + 2) ^ xk) * 16)) = vr2;
      *(uint4*)(xd + (((q * 4 + 3) ^ xk) * 16)) = vr3;
    }
    __syncthreads();   // xs[cb+1] (and W) visible for next iteration
  }
}

// ---------- combine: relu(segsum(msg)*inv + x@self_w + bias) via MFMA ----------
#define ACC8(M, B_) \
  ms[(B_) + 0] += bf2f((M).x & 0xffffu); ms[(B_) + 1] += bf2f((M).x >> 16); \
  ms[(B_) + 2] += bf2f((M).y & 0xffffu); ms[(B_) + 3] += bf2f((M).y >> 16); \
  ms[(B_) + 4] += bf2f((M).z & 0xffffu); ms[(B_) + 5] += bf2f((M).z >> 16); \
  ms[(B_) + 6] += bf2f((M).w & 0xffffu); ms[(B_) + 7] += bf2f((M).w >> 16);

__launch_bounds__(512, 4)
__global__ void k_combM(const u16* __restrict__ xbf, const u16* __restrict__ swt,
                        const float* __restrict__ bias_l, const u16* __restrict__ msg,
                        const int* __restrict__ row_ptr, const int* __restrict__ indeg,
                        float* __restrict__ outf, u16* __restrict__ outb, int last) {
  __shared__ __align__(16) char smem[65536];
  int tid = threadIdx.x;
  int r0 = blockIdx.x * 128;
  {
    const char* wg = (const char*)swt;
    const char* xg = (const char*)(xbf + (size_t)r0 * DIM);
#pragma unroll
    for (int it = 0; it < 4; ++it) {
      int off = it * 8192 + tid * 16;
      GLD16(wg + off, smem + off);
      GLD16(xg + off, smem + 32768 + off);
    }
  }
  __syncthreads();
  int w = tid >> 6, l = tid & 63;
  int lr = l & 31, hi = l >> 5;
  int dt = w & 3;
  int d = dt * 32 + lr;
  int e1 = (w >> 2) * 32 + lr;
  const char* wb = smem;
  const char* xb = smem + 32768;
  f32x16 accA, accB;
#pragma unroll
  for (int i = 0; i < 16; ++i) { accA[i] = 0.f; accB[i] = 0.f; }
  int aswz = d & 7, bswz = lr & 7;
#pragma unroll
  for (int s = 0; s < 8; ++s) {
    int c = s * 2 + hi;
    bf16x8 av = *(const bf16x8*)(wb + d * 256 + ((c ^ aswz) * 16));
    bf16x8 b1 = *(const bf16x8*)(xb + e1 * 256 + ((c ^ bswz) * 16));
    bf16x8 b2 = *(const bf16x8*)(xb + (e1 + 64) * 256 + ((c ^ bswz) * 16));
    accA = __builtin_amdgcn_mfma_f32_32x32x16_bf16(av, b1, accA, 0, 0, 0);
    accB = __builtin_amdgcn_mfma_f32_32x32x16_bf16(av, b2, accB, 0, 0, 0);
  }
#pragma unroll
  for (int t = 0; t < 2; ++t) {
    int ent = r0 + e1 + t * 64;
    int vald = (ent < NENT);
    int eb = vald ? row_ptr[ent] : 0;
    int dg = vald ? indeg[ent] : 0;
    float inv = 1.f / (float)(dg > 1 ? dg : 1);
    float ms[16];
#pragma unroll
    for (int i = 0; i < 16; ++i) ms[i] = 0.f;
    const u16* mp = msg + (size_t)eb * DIM + dt * 32 + hi * 16;
    int j = 0;
    for (; j + 1 < dg; j += 2) {
      uint4 m1 = *(const uint4*)(mp);
      uint4 m2 = *(const uint4*)(mp + 8);
      uint4 m3 = *(const uint4*)(mp + DIM);
      uint4 m4 = *(const uint4*)(mp + DIM + 8);
      ACC8(m1, 0) ACC8(m2, 8) ACC8(m3, 0) ACC8(m4, 8)
      mp += 2 * DIM;
    }
    if (j < dg) {
      uint4 m1 = *(const uint4*)(mp);
      uint4 m2 = *(const uint4*)(mp + 8);
      ACC8(m1, 0) ACC8(m2, 8)
    }
    if (vald) {
#pragma unroll
      for (int q = 0; q < 4; ++q) {
        float4 bi = *(const float4*)(bias_l + dt * 32 + hi * 4 + 8 * q);
        float a0 = t ? accB[4 * q + 0] : accA[4 * q + 0];
        float a1 = t ? accB[4 * q + 1] : accA[4 * q + 1];
        float a2 = t ? accB[4 * q + 2] : accA[4 * q + 2];
        float a3 = t ? accB[4 * q + 3] : accA[4 * q + 3];
        float o0 = fmaxf(ms[4 * q + 0] * inv + a0 + bi.x, 0.f);
        float o1 = fmaxf(ms[4 * q + 1] * inv + a1 + bi.y, 0.f);
        float o2 = fmaxf(ms[4 * q + 2] * inv + a2 + bi.z, 0.f);
        float o3 = fmaxf(ms[4 * q + 3] * inv + a3 + bi.w, 0.f);
        if (last) {
          float4 o = make_float4(o0, o1, o2, o3);
          *(float4*)(outf + (size_t)ent * DIM + dt * 32 + hi * 4 + 8 * q) = o;
        } else {
          int c16 = 4 * dt + q;
          uint2 o;
          o.x = pk2(o0, o1); o.y = pk2(o2, o3);
          *(uint2*)(outb + (size_t)ent * DIM + ((c16 ^ (ent & 7)) * 8) + 4 * hi) = o;
        }
      }
    }
  }
}

extern "C" void kernel_launch(void* const* d_in, const int* in_sizes, int n_in,
                              void* d_out, int out_size, void* d_ws, size_t ws_size,
                              hipStream_t stream) {
  const float* x0    = (const float*)d_in[0];
  const float* bases = (const float*)d_in[1];
  const float* coefs = (const float*)d_in[2];
  const float* selfw = (const float*)d_in[3];
  const float* bias  = (const float*)d_in[4];
  const int* src = (const int*)d_in[5];
  const int* tgt = (const int*)d_in[6];
  const int* rel = (const int*)d_in[7];
  float* out = (float*)d_out;

  char* ws = (char*)d_ws;
  size_t off = 0;
  auto alloc = [&](size_t bytes) -> void* {
    void* p = ws + off;
    off = (off + bytes + 255) & ~(size_t)255;
    return p;
  };
  u16* Wt   = (u16*)alloc((size_t)NREL * DIM * DIM * 2);      // 3.3 MB
  u16* swt  = (u16*)alloc((size_t)2 * DIM * DIM * 2);         // 64 KB
  u16* xbf  = (u16*)alloc((size_t)NENTPAD * DIM * 2);         // 25.6 MB
  u16* msg  = (u16*)alloc((size_t)NEDGES * DIM * 2);          // 153.6 MB
  int* es      = (int*)alloc((size_t)PADE * sizeof(int));
  int* tp      = (int*)alloc((size_t)PADE * sizeof(int));
  int* indeg   = (int*)alloc((size_t)NENT * sizeof(int));
  int* row_ptr = (int*)alloc((size_t)NENT * sizeof(int));
  int* loc     = (int*)alloc((size_t)NENT * sizeof(int));
  int* fill_t  = (int*)alloc((size_t)NENT * sizeof(int));
  int* bsum    = (int*)alloc(128 * sizeof(int));
  int* hist    = (int*)alloc((size_t)NREL * NBH * sizeof(int));
  int* chunk_rel   = (int*)alloc(TMAX * sizeof(int));
  int* chunk_start = (int*)alloc(TMAX * sizeof(int));
  int* chunk_valid = (int*)alloc(TMAX * sizeof(int));
  int* chunkT      = (int*)alloc(sizeof(int));

  hipMemsetAsync(indeg, 0, (size_t)NENT * sizeof(int), stream);
  hipMemsetAsync(fill_t, 0, (size_t)NENT * sizeof(int), stream);

  k_hist2<<<NBH, 1024, 0, stream>>>(tgt, rel, indeg, hist);
  k_scan2<<<1, 1024, 0, stream>>>(hist, chunk_rel, chunk_start, chunk_valid, chunkT);
  k_escanA<<<NB_ESCAN, 256, 0, stream>>>(indeg, loc, bsum);
  k_escanC<<<(NENT + 255) / 256, 256, 0, stream>>>(loc, bsum, row_ptr);
  k_scatter2<<<NBH, 1024, 0, stream>>>(src, tgt, rel, hist, row_ptr, fill_t, es, tp);
  k_tobf<<<(NENT * 16) / 256, 256, 0, stream>>>(x0, xbf);
  k_swtT<<<16, 256, 0, stream>>>(selfw, swt);

  for (int l = 0; l < 2; ++l) {
    k_wmatT<<<(NREL * 2048) / 256, 256, 0, stream>>>(bases, coefs + l * NREL * NBASES, Wt);
    k_edgeP<<<NPERS, 512, 0, stream>>>(xbf, Wt, es, tp,
                                       chunk_rel, chunk_start, chunk_valid, chunkT, msg);
    k_combM<<<NENTPAD / 128, 512, 0, stream>>>(xbf, swt + (size_t)l * DIM * DIM,
                                               bias + l * DIM, msg, row_ptr, indeg,
                                               out, xbf, l == 0 ? 0 : 1);
  }
}